// Round 9
// baseline (284.871 us; speedup 1.0000x reference)
//
#include <hip/hip_runtime.h>
#include <stdint.h>

// Problem constants
#define Bdim 4
#define Nseq 2048
#define Dmod 1024
#define Hn   16
#define HD   64
#define SCALE 0.03125f   // D^-0.5 = 1/32
#define L2E   1.44269504089f

typedef __attribute__((ext_vector_type(8))) short short8;
typedef __attribute__((ext_vector_type(8))) unsigned short ushort8;
typedef __attribute__((ext_vector_type(4))) float f32x4;
typedef __attribute__((ext_vector_type(16))) float f32x16;

typedef __attribute__((address_space(3))) uint32_t lds_u32;
typedef __attribute__((address_space(1))) const uint32_t glob_u32;

static __device__ __forceinline__ void gload_lds16(const unsigned short* g, unsigned short* l) {
    __builtin_amdgcn_global_load_lds((glob_u32*)(const void*)g, (lds_u32*)(void*)l, 16, 0, 0);
}

static __device__ __forceinline__ unsigned short f2bf(float f) {
    union { float f; uint32_t u; } v; v.f = f;
    uint32_t r = (v.u + 0x7FFFu + ((v.u >> 16) & 1u)) >> 16;
    return (unsigned short)r;
}

// ---------------- cast x (fp32 -> bf16), vectorized ----------------
__global__ __launch_bounds__(256) void cast_x_kernel(const float* __restrict__ in,
                                                     unsigned short* __restrict__ out, int n4) {
    int i = blockIdx.x * blockDim.x + threadIdx.x;
    int stride = gridDim.x * blockDim.x;
    for (; i < n4; i += stride) {
        float4 v = reinterpret_cast<const float4*>(in)[i];
        ushort4 o;
        o.x = f2bf(v.x); o.y = f2bf(v.y); o.z = f2bf(v.z); o.w = f2bf(v.w);
        reinterpret_cast<ushort4*>(out)[i] = o;
    }
}

// ---------------- transpose + cast weights: out[c][r] = in[r][c] ----------------
__global__ void transpose_cast_kernel(const float* __restrict__ in,
                                      unsigned short* __restrict__ out, int R, int C) {
    __shared__ unsigned short t[32][33];
    int c0 = blockIdx.x * 32, r0 = blockIdx.y * 32;
    int tx = threadIdx.x, ty = threadIdx.y;
#pragma unroll
    for (int i = 0; i < 4; ++i)
        t[ty + i*8][tx] = f2bf(in[(size_t)(r0 + ty + i*8) * C + c0 + tx]);
    __syncthreads();
#pragma unroll
    for (int i = 0; i < 4; ++i)
        out[(size_t)(c0 + ty + i*8) * R + r0 + tx] = t[tx][ty + i*8];
}

// ---------------- bf16 GEMM (m97 structure + XCD remap + optional V->vT redirect) ----------------
template<bool OUT_BF16, bool BIAS, bool VSPLIT>
__global__ __launch_bounds__(256) void gemm_bt_kernel(const unsigned short* __restrict__ A,
                                                      const unsigned short* __restrict__ Bt,
                                                      void* __restrict__ Cv,
                                                      const float* __restrict__ bias,
                                                      unsigned short* __restrict__ vTp,
                                                      int M, int N, int K) {
    __shared__ unsigned short Al[128 * 64];
    __shared__ unsigned short Bl[128 * 64];
    int tid = threadIdx.x;
    int lane = tid & 63, wv = tid >> 6;
    int wr = (wv >> 1) * 64, wc = (wv & 1) * 64;
    int lr = lane & 15, lg = lane >> 4, lk = lg * 8;

    int gx = gridDim.x;
    int lin = blockIdx.y * gx + blockIdx.x;
    int cpx = (gx * gridDim.y) >> 3;
    int nl = (lin & 7) * cpx + (lin >> 3);
    int m0 = (nl / gx) * 128, n0 = (nl % gx) * 128;

    int srow = wv * 8 + (lane >> 3);
    int scol = (lane & 7) * 8;
    const unsigned short* ag = A  + (size_t)(m0 + srow) * K + scol;
    const unsigned short* bg = Bt + (size_t)(n0 + srow) * K + scol;
    unsigned short* la = Al + wv * 512;
    unsigned short* lb = Bl + wv * 512;

    f32x4 acc[4][4];
#pragma unroll
    for (int i = 0; i < 4; ++i)
#pragma unroll
        for (int j = 0; j < 4; ++j) acc[i][j] = (f32x4)0.f;

    for (int k0 = 0; k0 < K; k0 += 64) {
        __syncthreads();
#pragma unroll
        for (int i = 0; i < 4; ++i) {
            gload_lds16(ag + (size_t)i * 32 * K + k0, la + i * 2048);
            gload_lds16(bg + (size_t)i * 32 * K + k0, lb + i * 2048);
        }
        __syncthreads();
#pragma unroll
        for (int ks = 0; ks < 2; ++ks) {
            short8 a[4], b[4];
#pragma unroll
            for (int mi = 0; mi < 4; ++mi)
                a[mi] = *reinterpret_cast<const short8*>(Al + (wr + mi*16 + lr) * 64 + ks*32 + lk);
#pragma unroll
            for (int nj = 0; nj < 4; ++nj)
                b[nj] = *reinterpret_cast<const short8*>(Bl + (wc + nj*16 + lr) * 64 + ks*32 + lk);
#pragma unroll
            for (int mi = 0; mi < 4; ++mi)
#pragma unroll
                for (int nj = 0; nj < 4; ++nj)
                    acc[mi][nj] = __builtin_amdgcn_mfma_f32_16x16x32_bf16(a[mi], b[nj], acc[mi][nj], 0, 0, 0);
        }
    }
#pragma unroll
    for (int mi = 0; mi < 4; ++mi) {
#pragma unroll
        for (int nj = 0; nj < 4; ++nj) {
            int r = m0 + wr + mi*16 + lg*4;
            int c = n0 + wc + nj*16 + lr;
            if (VSPLIT && c >= 2048) {
                int cc = c - 2048;
                int bh = ((r >> 11) << 4) + (cc >> 6);
                int d = cc & 63;
                ushort4 o4;
                o4.x = f2bf(acc[mi][nj][0]);
                o4.y = f2bf(acc[mi][nj][1]);
                o4.z = f2bf(acc[mi][nj][2]);
                o4.w = f2bf(acc[mi][nj][3]);
                *reinterpret_cast<ushort4*>(vTp + ((size_t)(bh * 64 + d) * 2048) + (r & 2047)) = o4;
            } else {
                float bv = BIAS ? bias[c] : 0.f;
#pragma unroll
                for (int i = 0; i < 4; ++i) {
                    float v = acc[mi][nj][i] + bv;
                    if (OUT_BF16)
                        reinterpret_cast<unsigned short*>(Cv)[(size_t)(r + i) * N + c] = f2bf(v);
                    else
                        reinterpret_cast<float*>(Cv)[(size_t)(r + i) * N + c] = v;
                }
            }
        }
    }
}

// ---------------- flash attention: software-pipelined QK(t+1) || softmax(t) || PV(t) ----------------
// 64 q/wave (2 subtiles), in-register P (R8-verified exchange), fragment-linear LDS,
// K double-buffered + V triple-buffered, global_load_lds width-16 staging, 1 barrier/tile.
__global__ __launch_bounds__(256, 2) void attn_kernel(const unsigned short* __restrict__ qkv,
                                                      const unsigned short* __restrict__ vT,
                                                      unsigned short* __restrict__ attn_o) {
    __shared__ unsigned short Kl[2 * 64 * 64];   // 16 KB
    __shared__ unsigned short Vl[3 * 64 * 64];   // 24 KB

    // bijective XCD-chunked swizzle: 512 blocks = 8 XCDs x 64
    int w = blockIdx.x;
    int lid = (w & 7) * 64 + (w >> 3);
    int bh = lid >> 3, qb = lid & 7;
    int b = bh >> 4, h = bh & 15;

    int tid = threadIdx.x, lane = tid & 63, wv = tid >> 6;
    int lr = lane & 31, hi = lane >> 5;
    int q0 = qb * 256 + wv * 64;

    // Q b-frags for both subtiles
    short8 qfA[4], qfB[4];
    {
        const unsigned short* qrowA = qkv + (size_t)(b * Nseq + q0 + lr) * 3072 + h * 64 + hi * 8;
        const unsigned short* qrowB = qrowA + (size_t)32 * 3072;
#pragma unroll
        for (int ks = 0; ks < 4; ++ks) {
            qfA[ks] = *reinterpret_cast<const short8*>(qrowA + ks * 16);
            qfB[ks] = *reinterpret_cast<const short8*>(qrowB + ks * 16);
        }
    }

    float mrunA = -1e30f, lrunA = 0.f, mrunB = -1e30f, lrunB = 0.f;
    f32x16 oA0 = (f32x16)0.f, oA1 = (f32x16)0.f, oB0 = (f32x16)0.f, oB1 = (f32x16)0.f;

    // gload_lds staging: chunk ids c0 = wv*128+lane, c1 = c0+64 (chunk k = LDS offset k*16)
    int c0 = wv * 128 + lane, c1 = c0 + 64;
    int kv0 = ((c0 >> 8) << 5) + (c0 & 31), d00 = (((c0 >> 6) & 3) << 4) + (((c0 >> 5) & 1) << 3);
    int kv1 = ((c1 >> 8) << 5) + (c1 & 31), d01 = (((c1 >> 6) & 3) << 4) + (((c1 >> 5) & 1) << 3);
    const unsigned short* kp0 = qkv + (size_t)(b * Nseq + kv0) * 3072 + 1024 + h * 64 + d00;
    const unsigned short* kp1 = qkv + (size_t)(b * Nseq + kv1) * 3072 + 1024 + h * 64 + d01;
    const unsigned short* vp0 = vT + ((size_t)(bh * 64 + kv0)) * Nseq + d00;   // kv0 plays d, d00 plays kv-offset
    const unsigned short* vp1 = vT + ((size_t)(bh * 64 + kv1)) * Nseq + d01;
    unsigned short* kld = (unsigned short*)((char*)Kl + wv * 2048);
    unsigned short* vld = (unsigned short*)((char*)Vl + wv * 2048);

    // prologue: stage tiles 0 and 1
    gload_lds16(kp0, kld);            gload_lds16(kp1, kld + 512);
    gload_lds16(vp0, vld);            gload_lds16(vp1, vld + 512);
    kp0 += 64 * 3072; kp1 += 64 * 3072; vp0 += 64; vp1 += 64;
    gload_lds16(kp0, kld + 4096);     gload_lds16(kp1, kld + 4096 + 512);
    gload_lds16(vp0, vld + 4096);     gload_lds16(vp1, vld + 4096 + 512);
    kp0 += 64 * 3072; kp1 += 64 * 3072; vp0 += 64; vp1 += 64;
    __syncthreads();   // drains vmcnt -> tiles 0,1 resident

    f32x16 xA0, xA1, xB0, xB1, yA0, yA1, yB0, yB1;
    // QK(0) -> X bank
    xA0 = (f32x16)0.f; xA1 = (f32x16)0.f; xB0 = (f32x16)0.f; xB1 = (f32x16)0.f;
#pragma unroll
    for (int ks = 0; ks < 4; ++ks) {
        short8 kf0 = *reinterpret_cast<const short8*>((char*)Kl + ks*1024 + lane*16);
        short8 kf1 = *reinterpret_cast<const short8*>((char*)Kl + 4096 + ks*1024 + lane*16);
        xA0 = __builtin_amdgcn_mfma_f32_32x32x16_bf16(kf0, qfA[ks], xA0, 0, 0, 0);
        xA1 = __builtin_amdgcn_mfma_f32_32x32x16_bf16(kf1, qfA[ks], xA1, 0, 0, 0);
        xB0 = __builtin_amdgcn_mfma_f32_32x32x16_bf16(kf0, qfB[ks], xB0, 0, 0, 0);
        xB1 = __builtin_amdgcn_mfma_f32_32x32x16_bf16(kf1, qfB[ks], xB1, 0, 0, 0);
    }

    auto tile_body = [&](f32x16& SA0, f32x16& SA1, f32x16& SB0, f32x16& SB1,
                         f32x16& NA0, f32x16& NA1, f32x16& NB0, f32x16& NB1,
                         int t, int vro, int vwo) {
        __syncthreads();   // publishes tile t+1 staging; separates reads of bufs about to be overwritten

        // ---- issue gload staging of tile t+2 (K -> Kl[t&1], V -> Vl[(t+2)%3]) ----
        if (t < 30) {
            unsigned short* kd = (unsigned short*)((char*)Kl + (t & 1) * 8192 + wv * 2048);
            unsigned short* vd = (unsigned short*)((char*)Vl + vwo + wv * 2048);
            gload_lds16(kp0, kd);       gload_lds16(kp1, kd + 512);
            gload_lds16(vp0, vd);       gload_lds16(vp1, vd + 512);
            kp0 += 64 * 3072; kp1 += 64 * 3072; vp0 += 64; vp1 += 64;
        }

        // ---- QK(t+1) into N bank (MFMA pipe; overlaps softmax VALU below) ----
        if (t < 31) {
            char* kb = (char*)Kl + ((t + 1) & 1) * 8192;
            NA0 = (f32x16)0.f; NA1 = (f32x16)0.f; NB0 = (f32x16)0.f; NB1 = (f32x16)0.f;
#pragma unroll
            for (int ks = 0; ks < 4; ++ks) {
                short8 kf0 = *reinterpret_cast<const short8*>(kb + ks*1024 + lane*16);
                short8 kf1 = *reinterpret_cast<const short8*>(kb + 4096 + ks*1024 + lane*16);
                NA0 = __builtin_amdgcn_mfma_f32_32x32x16_bf16(kf0, qfA[ks], NA0, 0, 0, 0);
                NA1 = __builtin_amdgcn_mfma_f32_32x32x16_bf16(kf1, qfA[ks], NA1, 0, 0, 0);
                NB0 = __builtin_amdgcn_mfma_f32_32x32x16_bf16(kf0, qfB[ks], NB0, 0, 0, 0);
                NB1 = __builtin_amdgcn_mfma_f32_32x32x16_bf16(kf1, qfB[ks], NB1, 0, 0, 0);
            }
        }

        // ---- softmax(t) on S bank ----
        float tA[16], tB[16];
#pragma unroll
        for (int i = 0; i < 16; ++i) { tA[i] = fmaxf(SA0[i], SA1[i]); tB[i] = fmaxf(SB0[i], SB1[i]); }
#pragma unroll
        for (int st = 8; st > 0; st >>= 1)
#pragma unroll
            for (int i = 0; i < st; ++i) { tA[i] = fmaxf(tA[i], tA[i + st]); tB[i] = fmaxf(tB[i], tB[i + st]); }
        float mlocA = fmaxf(tA[0], __shfl_xor(tA[0], 32)) * SCALE;
        float mlocB = fmaxf(tB[0], __shfl_xor(tB[0], 32)) * SCALE;

        if (!__all((mlocA <= mrunA + 8.f) && (mlocB <= mrunB + 8.f))) {
            float mnA = fmaxf(mrunA, mlocA);
            float fA = __builtin_amdgcn_exp2f((mrunA - mnA) * L2E);
            float mnB = fmaxf(mrunB, mlocB);
            float fB = __builtin_amdgcn_exp2f((mrunB - mnB) * L2E);
            lrunA *= fA; lrunB *= fB; mrunA = mnA; mrunB = mnB;
#pragma unroll
            for (int i = 0; i < 16; ++i) {
                oA0[i] *= fA; oA1[i] *= fA; oB0[i] *= fB; oB1[i] *= fB;
            }
        }

        const float c1f = SCALE * L2E;
        float c0A = -mrunA * L2E, c0B = -mrunB * L2E;
        // exp in place: S bank becomes P
#pragma unroll
        for (int i = 0; i < 16; ++i) {
            SA0[i] = __builtin_amdgcn_exp2f(fmaf(SA0[i], c1f, c0A));
            SA1[i] = __builtin_amdgcn_exp2f(fmaf(SA1[i], c1f, c0A));
            SB0[i] = __builtin_amdgcn_exp2f(fmaf(SB0[i], c1f, c0B));
            SB1[i] = __builtin_amdgcn_exp2f(fmaf(SB1[i], c1f, c0B));
        }

        float aA[16], aB[16];
#pragma unroll
        for (int i = 0; i < 16; ++i) { aA[i] = SA0[i] + SA1[i]; aB[i] = SB0[i] + SB1[i]; }
#pragma unroll
        for (int st = 8; st > 0; st >>= 1)
#pragma unroll
            for (int i = 0; i < st; ++i) { aA[i] += aA[i + st]; aB[i] += aB[i + st]; }
        lrunA += aA[0] + __shfl_xor(aA[0], 32);
        lrunB += aB[0] + __shfl_xor(aB[0], 32);

        // ---- pack P pairs to bf16 words ----
        uint32_t UA[16], UB[16];
#pragma unroll
        for (int m = 0; m < 8; ++m) {
            asm("v_cvt_pk_bf16_f32 %0, %1, %2" : "=v"(UA[m])   : "v"(SA0[2*m]), "v"(SA0[2*m+1]));
            asm("v_cvt_pk_bf16_f32 %0, %1, %2" : "=v"(UA[8+m]) : "v"(SA1[2*m]), "v"(SA1[2*m+1]));
            asm("v_cvt_pk_bf16_f32 %0, %1, %2" : "=v"(UB[m])   : "v"(SB0[2*m]), "v"(SB0[2*m+1]));
            asm("v_cvt_pk_bf16_f32 %0, %1, %2" : "=v"(UB[8+m]) : "v"(SB1[2*m]), "v"(SB1[2*m+1]));
        }
        // ---- cross-half exchange (select-before-shuffle), R8-verified ----
        uint32_t rvA[8], rvB[8];
#pragma unroll
        for (int g = 0; g < 2; ++g) {
            const int o = g * 8, ro = g * 4;
            rvA[ro+0] = (uint32_t)__shfl_xor((int)(hi ? UA[o+0] : UA[o+2]), 32);
            rvA[ro+1] = (uint32_t)__shfl_xor((int)(hi ? UA[o+1] : UA[o+3]), 32);
            rvA[ro+2] = (uint32_t)__shfl_xor((int)(hi ? UA[o+4] : UA[o+6]), 32);
            rvA[ro+3] = (uint32_t)__shfl_xor((int)(hi ? UA[o+5] : UA[o+7]), 32);
            rvB[ro+0] = (uint32_t)__shfl_xor((int)(hi ? UB[o+0] : UB[o+2]), 32);
            rvB[ro+1] = (uint32_t)__shfl_xor((int)(hi ? UB[o+1] : UB[o+3]), 32);
            rvB[ro+2] = (uint32_t)__shfl_xor((int)(hi ? UB[o+4] : UB[o+6]), 32);
            rvB[ro+3] = (uint32_t)__shfl_xor((int)(hi ? UB[o+5] : UB[o+7]), 32);
        }

        // ---- PV(t): V from Vl[t%3], P frags assembled per same sigma ----
        char* vb = (char*)Vl + vro;
        __builtin_amdgcn_s_setprio(1);
#pragma unroll
        for (int ks4 = 0; ks4 < 4; ++ks4) {
            const int hh = 8*(ks4>>1) + 4*(ks4&1);
            const int rc = 4*(ks4>>1) + 2*(ks4&1);
            union { uint32_t u[4]; short8 s; } fA, fB;
            fA.u[0] = hi ? rvA[rc]    : UA[hh];
            fA.u[1] = hi ? rvA[rc+1]  : UA[hh+1];
            fA.u[2] = hi ? UA[hh+2]   : rvA[rc];
            fA.u[3] = hi ? UA[hh+3]   : rvA[rc+1];
            fB.u[0] = hi ? rvB[rc]    : UB[hh];
            fB.u[1] = hi ? rvB[rc+1]  : UB[hh+1];
            fB.u[2] = hi ? UB[hh+2]   : rvB[rc];
            fB.u[3] = hi ? UB[hh+3]   : rvB[rc+1];
            short8 vf0 = *reinterpret_cast<const short8*>(vb + ks4*1024 + lane*16);
            short8 vf1 = *reinterpret_cast<const short8*>(vb + 4096 + ks4*1024 + lane*16);
            oA0 = __builtin_amdgcn_mfma_f32_32x32x16_bf16(vf0, fA.s, oA0, 0, 0, 0);
            oA1 = __builtin_amdgcn_mfma_f32_32x32x16_bf16(vf1, fA.s, oA1, 0, 0, 0);
            oB0 = __builtin_amdgcn_mfma_f32_32x32x16_bf16(vf0, fB.s, oB0, 0, 0, 0);
            oB1 = __builtin_amdgcn_mfma_f32_32x32x16_bf16(vf1, fB.s, oB1, 0, 0, 0);
        }
        __builtin_amdgcn_s_setprio(0);
    };

    int vro = 0, vwo = 16384;
    for (int t = 0; t < 32; t += 2) {
        tile_body(xA0, xA1, xB0, xB1, yA0, yA1, yB0, yB1, t, vro, vwo);
        vro = (vro == 16384) ? 0 : vro + 8192;
        vwo = (vwo == 16384) ? 0 : vwo + 8192;
        tile_body(yA0, yA1, yB0, yB1, xA0, xA1, xB0, xB1, t + 1, vro, vwo);
        vro = (vro == 16384) ? 0 : vro + 8192;
        vwo = (vwo == 16384) ? 0 : vwo + 8192;
    }

    // ---- epilogue ----
    float invA = 1.f / lrunA, invB = 1.f / lrunB;
    unsigned short* orowA = attn_o + (size_t)(b * Nseq + q0 + lr) * Dmod + h * 64;
    unsigned short* orowB = attn_o + (size_t)(b * Nseq + q0 + 32 + lr) * Dmod + h * 64;
#pragma unroll
    for (int db = 0; db < 2; ++db)
#pragma unroll
        for (int g = 0; g < 4; ++g) {
            int d = db * 32 + 8 * g + 4 * hi;
            ushort4 o4;
            o4.x = f2bf((db ? oA1[4*g+0] : oA0[4*g+0]) * invA);
            o4.y = f2bf((db ? oA1[4*g+1] : oA0[4*g+1]) * invA);
            o4.z = f2bf((db ? oA1[4*g+2] : oA0[4*g+2]) * invA);
            o4.w = f2bf((db ? oA1[4*g+3] : oA0[4*g+3]) * invA);
            *reinterpret_cast<ushort4*>(orowA + d) = o4;
            o4.x = f2bf((db ? oB1[4*g+0] : oB0[4*g+0]) * invB);
            o4.y = f2bf((db ? oB1[4*g+1] : oB0[4*g+1]) * invB);
            o4.z = f2bf((db ? oB1[4*g+2] : oB0[4*g+2]) * invB);
            o4.w = f2bf((db ? oB1[4*g+3] : oB0[4*g+3]) * invB);
            *reinterpret_cast<ushort4*>(orowB + d) = o4;
        }
}

// ---------------- launch ----------------
extern "C" void kernel_launch(void* const* d_in, const int* in_sizes, int n_in,
                              void* d_out, int out_size, void* d_ws, size_t ws_size,
                              hipStream_t stream) {
    const float* x      = (const float*)d_in[0];
    const float* w_qkv  = (const float*)d_in[1];
    const float* w_proj = (const float*)d_in[2];
    const float* b_proj = (const float*)d_in[3];
    float* out = (float*)d_out;
    char* ws = (char*)d_ws;

    unsigned short* qkv    = (unsigned short*)(ws);               // 50331648 B (V third unused)
    unsigned short* vT     = (unsigned short*)(ws + 50331648);    // 16777216 B
    unsigned short* xb     = (unsigned short*)(ws + 67108864);    // 16777216 B (reused as attn_o)
    unsigned short* attn_o = xb;
    unsigned short* wqkvT  = (unsigned short*)(ws + 83886080);    // 6291456 B
    unsigned short* wprojT = (unsigned short*)(ws + 90177536);    // 2097152 B

    cast_x_kernel<<<2048, 256, 0, stream>>>(x, xb, (Bdim*Nseq*Dmod)/4);
    transpose_cast_kernel<<<dim3(3072/32, 1024/32), dim3(32, 8), 0, stream>>>(w_qkv, wqkvT, 1024, 3072);
    transpose_cast_kernel<<<dim3(1024/32, 1024/32), dim3(32, 8), 0, stream>>>(w_proj, wprojT, 1024, 1024);
    // qkv = x @ w_qkv; V columns redirected (transposed) into vT
    gemm_bt_kernel<true, false, true><<<dim3(3072/128, 8192/128), 256, 0, stream>>>(
        xb, wqkvT, qkv, nullptr, vT, Bdim*Nseq, 3*Dmod, Dmod);
    attn_kernel<<<512, 256, 0, stream>>>(qkv, vT, attn_o);
    gemm_bt_kernel<false, true, false><<<dim3(1024/128, 8192/128), 256, 0, stream>>>(
        attn_o, wprojT, out, b_proj, nullptr, Bdim*Nseq, Dmod, Dmod);
}

// Round 10
// 232.420 us; speedup vs baseline: 1.2257x; 1.2257x over previous
//
#include <hip/hip_runtime.h>
#include <stdint.h>

// Problem constants
#define Bdim 4
#define Nseq 2048
#define Dmod 1024
#define Hn   16
#define HD   64
#define SCALE 0.03125f   // D^-0.5 = 1/32
#define L2E   1.44269504089f

typedef __attribute__((ext_vector_type(8))) short short8;
typedef __attribute__((ext_vector_type(8))) unsigned short ushort8;
typedef __attribute__((ext_vector_type(4))) float f32x4;
typedef __attribute__((ext_vector_type(16))) float f32x16;

typedef __attribute__((address_space(3))) uint32_t lds_u32;
typedef __attribute__((address_space(1))) const uint32_t glob_u32;

static __device__ __forceinline__ void gload_lds16(const unsigned short* g, unsigned short* l) {
    __builtin_amdgcn_global_load_lds((glob_u32*)(const void*)g, (lds_u32*)(void*)l, 16, 0, 0);
}

static __device__ __forceinline__ unsigned short f2bf(float f) {
    union { float f; uint32_t u; } v; v.f = f;
    uint32_t r = (v.u + 0x7FFFu + ((v.u >> 16) & 1u)) >> 16;
    return (unsigned short)r;
}

// ---------------- cast x (fp32 -> bf16), vectorized ----------------
__global__ __launch_bounds__(256) void cast_x_kernel(const float* __restrict__ in,
                                                     unsigned short* __restrict__ out, int n4) {
    int i = blockIdx.x * blockDim.x + threadIdx.x;
    int stride = gridDim.x * blockDim.x;
    for (; i < n4; i += stride) {
        float4 v = reinterpret_cast<const float4*>(in)[i];
        ushort4 o;
        o.x = f2bf(v.x); o.y = f2bf(v.y); o.z = f2bf(v.z); o.w = f2bf(v.w);
        reinterpret_cast<ushort4*>(out)[i] = o;
    }
}

// ---------------- transpose + cast weights: out[c][r] = in[r][c] ----------------
__global__ void transpose_cast_kernel(const float* __restrict__ in,
                                      unsigned short* __restrict__ out, int R, int C) {
    __shared__ unsigned short t[32][33];
    int c0 = blockIdx.x * 32, r0 = blockIdx.y * 32;
    int tx = threadIdx.x, ty = threadIdx.y;
#pragma unroll
    for (int i = 0; i < 4; ++i)
        t[ty + i*8][tx] = f2bf(in[(size_t)(r0 + ty + i*8) * C + c0 + tx]);
    __syncthreads();
#pragma unroll
    for (int i = 0; i < 4; ++i)
        out[(size_t)(c0 + ty + i*8) * R + r0 + tx] = t[tx][ty + i*8];
}

// ---------------- bf16 GEMM (m97 structure + XCD remap + optional V->vT redirect) ----------------
template<bool OUT_BF16, bool BIAS, bool VSPLIT>
__global__ __launch_bounds__(256) void gemm_bt_kernel(const unsigned short* __restrict__ A,
                                                      const unsigned short* __restrict__ Bt,
                                                      void* __restrict__ Cv,
                                                      const float* __restrict__ bias,
                                                      unsigned short* __restrict__ vTp,
                                                      int M, int N, int K) {
    __shared__ unsigned short Al[128 * 64];
    __shared__ unsigned short Bl[128 * 64];
    int tid = threadIdx.x;
    int lane = tid & 63, wv = tid >> 6;
    int wr = (wv >> 1) * 64, wc = (wv & 1) * 64;
    int lr = lane & 15, lg = lane >> 4, lk = lg * 8;

    int gx = gridDim.x;
    int lin = blockIdx.y * gx + blockIdx.x;
    int cpx = (gx * gridDim.y) >> 3;
    int nl = (lin & 7) * cpx + (lin >> 3);
    int m0 = (nl / gx) * 128, n0 = (nl % gx) * 128;

    int srow = wv * 8 + (lane >> 3);
    int scol = (lane & 7) * 8;
    const unsigned short* ag = A  + (size_t)(m0 + srow) * K + scol;
    const unsigned short* bg = Bt + (size_t)(n0 + srow) * K + scol;
    unsigned short* la = Al + wv * 512;
    unsigned short* lb = Bl + wv * 512;

    f32x4 acc[4][4];
#pragma unroll
    for (int i = 0; i < 4; ++i)
#pragma unroll
        for (int j = 0; j < 4; ++j) acc[i][j] = (f32x4)0.f;

    for (int k0 = 0; k0 < K; k0 += 64) {
        __syncthreads();
#pragma unroll
        for (int i = 0; i < 4; ++i) {
            gload_lds16(ag + (size_t)i * 32 * K + k0, la + i * 2048);
            gload_lds16(bg + (size_t)i * 32 * K + k0, lb + i * 2048);
        }
        __syncthreads();
#pragma unroll
        for (int ks = 0; ks < 2; ++ks) {
            short8 a[4], b[4];
#pragma unroll
            for (int mi = 0; mi < 4; ++mi)
                a[mi] = *reinterpret_cast<const short8*>(Al + (wr + mi*16 + lr) * 64 + ks*32 + lk);
#pragma unroll
            for (int nj = 0; nj < 4; ++nj)
                b[nj] = *reinterpret_cast<const short8*>(Bl + (wc + nj*16 + lr) * 64 + ks*32 + lk);
#pragma unroll
            for (int mi = 0; mi < 4; ++mi)
#pragma unroll
                for (int nj = 0; nj < 4; ++nj)
                    acc[mi][nj] = __builtin_amdgcn_mfma_f32_16x16x32_bf16(a[mi], b[nj], acc[mi][nj], 0, 0, 0);
        }
    }
#pragma unroll
    for (int mi = 0; mi < 4; ++mi) {
#pragma unroll
        for (int nj = 0; nj < 4; ++nj) {
            int r = m0 + wr + mi*16 + lg*4;
            int c = n0 + wc + nj*16 + lr;
            if (VSPLIT && c >= 2048) {
                int cc = c - 2048;
                int bh = ((r >> 11) << 4) + (cc >> 6);
                int d = cc & 63;
                ushort4 o4;
                o4.x = f2bf(acc[mi][nj][0]);
                o4.y = f2bf(acc[mi][nj][1]);
                o4.z = f2bf(acc[mi][nj][2]);
                o4.w = f2bf(acc[mi][nj][3]);
                *reinterpret_cast<ushort4*>(vTp + ((size_t)(bh * 64 + d) * 2048) + (r & 2047)) = o4;
            } else {
                float bv = BIAS ? bias[c] : 0.f;
#pragma unroll
                for (int i = 0; i < 4; ++i) {
                    float v = acc[mi][nj][i] + bv;
                    if (OUT_BF16)
                        reinterpret_cast<unsigned short*>(Cv)[(size_t)(r + i) * N + c] = f2bf(v);
                    else
                        reinterpret_cast<float*>(Cv)[(size_t)(r + i) * N + c] = v;
                }
            }
        }
    }
}

// ---------------- flash attention: 32 q/wave, 4 blocks/CU (TLP), gload_lds staging, in-reg P ----------------
// S^T = mfma(K, Q): lane owns q; kv(reg r) = (r&3)+8*(r>>2)+4*hi (+32 for s1).
// Fragment-linear LDS K/V tiles (conflict-free b128 reads, R9-verified decode);
// staging via global_load_lds width-16 (no ds_writes); P stays in registers (R8-verified
// select-before-shuffle exchange); dbuf K/V, single barrier per tile (drains staging).
__global__ __launch_bounds__(256, 4) void attn_kernel(const unsigned short* __restrict__ qkv,
                                                      const unsigned short* __restrict__ vT,
                                                      unsigned short* __restrict__ attn_o) {
    __shared__ unsigned short Kl[2 * 64 * 64];   // 16 KB (2 x 8 KB buffers)
    __shared__ unsigned short Vl[2 * 64 * 64];   // 16 KB

    // bijective XCD-chunked swizzle: 1024 blocks = 8 XCDs x 128; 16 consecutive lids share one bh
    int w = blockIdx.x;
    int lid = (w & 7) * 128 + (w >> 3);
    int bh = lid >> 4, qb = lid & 15;
    int b = bh >> 4, h = bh & 15;

    int tid = threadIdx.x, lane = tid & 63, wv = tid >> 6;
    int lr = lane & 31, hi = lane >> 5;
    int q0 = qb * 128 + wv * 32;

    // Q b-frags: qf[ks] elem j = Q[q0+lr][ks*16 + hi*8 + j]
    short8 qf[4];
    {
        const unsigned short* qrow = qkv + (size_t)(b * Nseq + q0 + lr) * 3072 + h * 64 + hi * 8;
#pragma unroll
        for (int ks = 0; ks < 4; ++ks)
            qf[ks] = *reinterpret_cast<const short8*>(qrow + ks * 16);
    }

    float mrun = -1e30f, lrun = 0.f;
    f32x16 o0 = (f32x16)0.f, o1 = (f32x16)0.f;

    // gload_lds staging: thread covers chunks c0 = wv*128+lane and c1 = c0+64 (chunk = 16 B)
    int c0 = wv * 128 + lane, c1 = c0 + 64;
    int kv0 = ((c0 >> 8) << 5) + (c0 & 31), d00 = (((c0 >> 6) & 3) << 4) + (((c0 >> 5) & 1) << 3);
    int kv1 = ((c1 >> 8) << 5) + (c1 & 31), d01 = (((c1 >> 6) & 3) << 4) + (((c1 >> 5) & 1) << 3);
    const unsigned short* kp0 = qkv + (size_t)(b * Nseq + kv0) * 3072 + 1024 + h * 64 + d00;
    const unsigned short* kp1 = qkv + (size_t)(b * Nseq + kv1) * 3072 + 1024 + h * 64 + d01;
    const unsigned short* vp0 = vT + ((size_t)(bh * 64 + kv0)) * Nseq + d00;   // kv0 is d-row, d00 is kv-col
    const unsigned short* vp1 = vT + ((size_t)(bh * 64 + kv1)) * Nseq + d01;

    // prologue: stage tile 0 into buffer 0
    {
        unsigned short* kd = (unsigned short*)((char*)Kl + wv * 2048);
        unsigned short* vd = (unsigned short*)((char*)Vl + wv * 2048);
        gload_lds16(kp0, kd);  gload_lds16(kp1, (unsigned short*)((char*)kd + 1024));
        gload_lds16(vp0, vd);  gload_lds16(vp1, (unsigned short*)((char*)vd + 1024));
        kp0 += 64 * 3072; kp1 += 64 * 3072; vp0 += 64; vp1 += 64;
    }
    __syncthreads();   // drains vmcnt: tile 0 resident

    for (int t = 0; t < 32; ++t) {
        int rb = (t & 1) * 8192;

        // ---- issue staging of tile t+1 into the other buffer (full epoch of latency cover) ----
        if (t < 31) {
            unsigned short* kd = (unsigned short*)((char*)Kl + (rb ^ 8192) + wv * 2048);
            unsigned short* vd = (unsigned short*)((char*)Vl + (rb ^ 8192) + wv * 2048);
            gload_lds16(kp0, kd);  gload_lds16(kp1, (unsigned short*)((char*)kd + 1024));
            gload_lds16(vp0, vd);  gload_lds16(vp1, (unsigned short*)((char*)vd + 1024));
            kp0 += 64 * 3072; kp1 += 64 * 3072; vp0 += 64; vp1 += 64;
        }

        // ---- S^T = K · Q^T : contiguous 1KB fragment reads, conflict-free ----
        f32x16 s0 = (f32x16)0.f, s1 = (f32x16)0.f;
        __builtin_amdgcn_s_setprio(1);
#pragma unroll
        for (int ks = 0; ks < 4; ++ks) {
            short8 kf0 = *reinterpret_cast<const short8*>((char*)Kl + rb + ks*1024 + lane*16);
            short8 kf1 = *reinterpret_cast<const short8*>((char*)Kl + rb + 4096 + ks*1024 + lane*16);
            s0 = __builtin_amdgcn_mfma_f32_32x32x16_bf16(kf0, qf[ks], s0, 0, 0, 0);
            s1 = __builtin_amdgcn_mfma_f32_32x32x16_bf16(kf1, qf[ks], s1, 0, 0, 0);
        }
        __builtin_amdgcn_s_setprio(0);

        // ---- per-lane tile max ----
        float tmx[16];
#pragma unroll
        for (int i = 0; i < 16; ++i) tmx[i] = fmaxf(s0[i], s1[i]);
#pragma unroll
        for (int st = 8; st > 0; st >>= 1)
#pragma unroll
            for (int i = 0; i < st; ++i) tmx[i] = fmaxf(tmx[i], tmx[i + st]);
        float mloc = fmaxf(tmx[0], __shfl_xor(tmx[0], 32)) * SCALE;

        // ---- defer-max (T13) ----
        if (!__all(mloc <= mrun + 8.f)) {
            float mn = fmaxf(mrun, mloc);
            float fc = __builtin_amdgcn_exp2f((mrun - mn) * L2E);
            lrun *= fc; mrun = mn;
#pragma unroll
            for (int i = 0; i < 16; ++i) { o0[i] *= fc; o1[i] *= fc; }
        }

        // ---- P = exp2(s*c1 + c0), in place ----
        const float c1f = SCALE * L2E;
        float c0f = -mrun * L2E;
#pragma unroll
        for (int i = 0; i < 16; ++i) {
            s0[i] = __builtin_amdgcn_exp2f(fmaf(s0[i], c1f, c0f));
            s1[i] = __builtin_amdgcn_exp2f(fmaf(s1[i], c1f, c0f));
        }

        float a[16];
#pragma unroll
        for (int i = 0; i < 16; ++i) a[i] = s0[i] + s1[i];
#pragma unroll
        for (int st = 8; st > 0; st >>= 1)
#pragma unroll
            for (int i = 0; i < st; ++i) a[i] += a[i + st];
        lrun += a[0] + __shfl_xor(a[0], 32);

        // ---- pack P pairs to bf16 words ----
        uint32_t U[16];
#pragma unroll
        for (int m = 0; m < 8; ++m) {
            asm("v_cvt_pk_bf16_f32 %0, %1, %2" : "=v"(U[m])   : "v"(s0[2*m]), "v"(s0[2*m+1]));
            asm("v_cvt_pk_bf16_f32 %0, %1, %2" : "=v"(U[8+m]) : "v"(s1[2*m]), "v"(s1[2*m+1]));
        }
        // ---- cross-half exchange (select-before-shuffle), R8-verified ----
        uint32_t rv[8];
#pragma unroll
        for (int g = 0; g < 2; ++g) {
            const int oo = g * 8, ro = g * 4;
            rv[ro+0] = (uint32_t)__shfl_xor((int)(hi ? U[oo+0] : U[oo+2]), 32);
            rv[ro+1] = (uint32_t)__shfl_xor((int)(hi ? U[oo+1] : U[oo+3]), 32);
            rv[ro+2] = (uint32_t)__shfl_xor((int)(hi ? U[oo+4] : U[oo+6]), 32);
            rv[ro+3] = (uint32_t)__shfl_xor((int)(hi ? U[oo+5] : U[oo+7]), 32);
        }

        // ---- O^T += V^T · P ----
        __builtin_amdgcn_s_setprio(1);
#pragma unroll
        for (int ks4 = 0; ks4 < 4; ++ks4) {
            const int hh = 8*(ks4>>1) + 4*(ks4&1);
            const int rc = 4*(ks4>>1) + 2*(ks4&1);
            union { uint32_t u[4]; short8 s; } f;
            f.u[0] = hi ? rv[rc]    : U[hh];
            f.u[1] = hi ? rv[rc+1]  : U[hh+1];
            f.u[2] = hi ? U[hh+2]   : rv[rc];
            f.u[3] = hi ? U[hh+3]   : rv[rc+1];
            short8 vf0 = *reinterpret_cast<const short8*>((char*)Vl + rb + ks4*1024 + lane*16);
            short8 vf1 = *reinterpret_cast<const short8*>((char*)Vl + rb + 4096 + ks4*1024 + lane*16);
            o0 = __builtin_amdgcn_mfma_f32_32x32x16_bf16(vf0, f.s, o0, 0, 0, 0);
            o1 = __builtin_amdgcn_mfma_f32_32x32x16_bf16(vf1, f.s, o1, 0, 0, 0);
        }
        __builtin_amdgcn_s_setprio(0);

        __syncthreads();   // drains this epoch's staging; all waves done with buf[t&1]
    }

    // ---- epilogue: O^T[d][q] -> attn_o[b*N + q][h*64 + d] ----
    float inv = 1.f / lrun;
    unsigned short* orow = attn_o + (size_t)(b * Nseq + q0 + lr) * Dmod + h * 64;
#pragma unroll
    for (int db = 0; db < 2; ++db)
#pragma unroll
        for (int g = 0; g < 4; ++g) {
            int d = db * 32 + 8 * g + 4 * hi;
            ushort4 o4;
            o4.x = f2bf((db ? o1[4*g+0] : o0[4*g+0]) * inv);
            o4.y = f2bf((db ? o1[4*g+1] : o0[4*g+1]) * inv);
            o4.z = f2bf((db ? o1[4*g+2] : o0[4*g+2]) * inv);
            o4.w = f2bf((db ? o1[4*g+3] : o0[4*g+3]) * inv);
            *reinterpret_cast<ushort4*>(orow + d) = o4;
        }
}

// ---------------- launch ----------------
extern "C" void kernel_launch(void* const* d_in, const int* in_sizes, int n_in,
                              void* d_out, int out_size, void* d_ws, size_t ws_size,
                              hipStream_t stream) {
    const float* x      = (const float*)d_in[0];
    const float* w_qkv  = (const float*)d_in[1];
    const float* w_proj = (const float*)d_in[2];
    const float* b_proj = (const float*)d_in[3];
    float* out = (float*)d_out;
    char* ws = (char*)d_ws;

    unsigned short* qkv    = (unsigned short*)(ws);               // 50331648 B (V third unused)
    unsigned short* vT     = (unsigned short*)(ws + 50331648);    // 16777216 B
    unsigned short* xb     = (unsigned short*)(ws + 67108864);    // 16777216 B (reused as attn_o)
    unsigned short* attn_o = xb;
    unsigned short* wqkvT  = (unsigned short*)(ws + 83886080);    // 6291456 B
    unsigned short* wprojT = (unsigned short*)(ws + 90177536);    // 2097152 B

    cast_x_kernel<<<2048, 256, 0, stream>>>(x, xb, (Bdim*Nseq*Dmod)/4);
    transpose_cast_kernel<<<dim3(3072/32, 1024/32), dim3(32, 8), 0, stream>>>(w_qkv, wqkvT, 1024, 3072);
    transpose_cast_kernel<<<dim3(1024/32, 1024/32), dim3(32, 8), 0, stream>>>(w_proj, wprojT, 1024, 1024);
    // qkv = x @ w_qkv; V columns redirected (transposed) into vT
    gemm_bt_kernel<true, false, true><<<dim3(3072/128, 8192/128), 256, 0, stream>>>(
        xb, wqkvT, qkv, nullptr, vT, Bdim*Nseq, 3*Dmod, Dmod);
    attn_kernel<<<1024, 256, 0, stream>>>(qkv, vT, attn_o);
    gemm_bt_kernel<false, true, false><<<dim3(1024/128, 8192/128), 256, 0, stream>>>(
        attn_o, wprojT, out, b_proj, nullptr, Bdim*Nseq, Dmod, Dmod);
}

// Round 13
// 220.709 us; speedup vs baseline: 1.2907x; 1.0531x over previous
//
#include <hip/hip_runtime.h>
#include <stdint.h>

// Problem constants
#define Bdim 4
#define Nseq 2048
#define Dmod 1024
#define Hn   16
#define HD   64
#define SCALE 0.03125f   // D^-0.5 = 1/32
#define L2E   1.44269504089f

typedef __attribute__((ext_vector_type(8))) short short8;
typedef __attribute__((ext_vector_type(8))) unsigned short ushort8;
typedef __attribute__((ext_vector_type(4))) float f32x4;
typedef __attribute__((ext_vector_type(16))) float f32x16;

typedef __attribute__((address_space(3))) uint32_t lds_u32;
typedef __attribute__((address_space(1))) const uint32_t glob_u32;

static __device__ __forceinline__ void gload_lds16(const unsigned short* g, unsigned short* l) {
    __builtin_amdgcn_global_load_lds((glob_u32*)(const void*)g, (lds_u32*)(void*)l, 16, 0, 0);
}

static __device__ __forceinline__ unsigned short f2bf(float f) {
    union { float f; uint32_t u; } v; v.f = f;
    uint32_t r = (v.u + 0x7FFFu + ((v.u >> 16) & 1u)) >> 16;
    return (unsigned short)r;
}

// ---------------- fused prep: cast x -> bf16, transpose+cast both weight matrices ----------------
// blocks [0,2048): cast x (grid-stride float4); [2048,5120): w_qkv^T; [5120,6144): w_proj^T
__global__ __launch_bounds__(256) void prep_kernel(const float* __restrict__ x,
                                                   const float* __restrict__ w_qkv,
                                                   const float* __restrict__ w_proj,
                                                   unsigned short* __restrict__ xb,
                                                   unsigned short* __restrict__ wqkvT,
                                                   unsigned short* __restrict__ wprojT) {
    __shared__ unsigned short t[32][33];
    int bid = blockIdx.x, tid = threadIdx.x;
    if (bid < 2048) {
        const int n4 = (Bdim * Nseq * Dmod) / 4;
        int i = bid * 256 + tid;
        for (; i < n4; i += 2048 * 256) {
            float4 v = reinterpret_cast<const float4*>(x)[i];
            ushort4 o;
            o.x = f2bf(v.x); o.y = f2bf(v.y); o.z = f2bf(v.z); o.w = f2bf(v.w);
            reinterpret_cast<ushort4*>(xb)[i] = o;
        }
        return;
    }
    // transpose branches: out[c][r] = in[r][c]
    const float* in;
    unsigned short* out;
    int R, C, c0, r0;
    if (bid < 5120) {
        int lin = bid - 2048;            // 3072 blocks: 96 x 32
        in = w_qkv; out = wqkvT; R = 1024; C = 3072;
        c0 = (lin % 96) * 32; r0 = (lin / 96) * 32;
    } else {
        int lin = bid - 5120;            // 1024 blocks: 32 x 32
        in = w_proj; out = wprojT; R = 1024; C = 1024;
        c0 = (lin % 32) * 32; r0 = (lin / 32) * 32;
    }
    int tx = tid & 31, ty = tid >> 5;    // 32 x 8, same mapping as old dim3(32,8)
#pragma unroll
    for (int i = 0; i < 4; ++i)
        t[ty + i*8][tx] = f2bf(in[(size_t)(r0 + ty + i*8) * C + c0 + tx]);
    __syncthreads();
#pragma unroll
    for (int i = 0; i < 4; ++i)
        out[(size_t)(c0 + ty + i*8) * R + r0 + tx] = t[tx][ty + i*8];
}

// ---------------- bf16 GEMM (m97 structure + XCD remap + optional V->vT redirect) ----------------
template<bool OUT_BF16, bool BIAS, bool VSPLIT>
__global__ __launch_bounds__(256) void gemm_bt_kernel(const unsigned short* __restrict__ A,
                                                      const unsigned short* __restrict__ Bt,
                                                      void* __restrict__ Cv,
                                                      const float* __restrict__ bias,
                                                      unsigned short* __restrict__ vTp,
                                                      int M, int N, int K) {
    __shared__ unsigned short Al[128 * 64];
    __shared__ unsigned short Bl[128 * 64];
    int tid = threadIdx.x;
    int lane = tid & 63, wv = tid >> 6;
    int wr = (wv >> 1) * 64, wc = (wv & 1) * 64;
    int lr = lane & 15, lg = lane >> 4, lk = lg * 8;

    int gx = gridDim.x;
    int lin = blockIdx.y * gx + blockIdx.x;
    int cpx = (gx * gridDim.y) >> 3;
    int nl = (lin & 7) * cpx + (lin >> 3);
    int m0 = (nl / gx) * 128, n0 = (nl % gx) * 128;

    int srow = wv * 8 + (lane >> 3);
    int scol = (lane & 7) * 8;
    const unsigned short* ag = A  + (size_t)(m0 + srow) * K + scol;
    const unsigned short* bg = Bt + (size_t)(n0 + srow) * K + scol;
    unsigned short* la = Al + wv * 512;
    unsigned short* lb = Bl + wv * 512;

    f32x4 acc[4][4];
#pragma unroll
    for (int i = 0; i < 4; ++i)
#pragma unroll
        for (int j = 0; j < 4; ++j) acc[i][j] = (f32x4)0.f;

    for (int k0 = 0; k0 < K; k0 += 64) {
        __syncthreads();
#pragma unroll
        for (int i = 0; i < 4; ++i) {
            gload_lds16(ag + (size_t)i * 32 * K + k0, la + i * 2048);
            gload_lds16(bg + (size_t)i * 32 * K + k0, lb + i * 2048);
        }
        __syncthreads();
#pragma unroll
        for (int ks = 0; ks < 2; ++ks) {
            short8 a[4], b[4];
#pragma unroll
            for (int mi = 0; mi < 4; ++mi)
                a[mi] = *reinterpret_cast<const short8*>(Al + (wr + mi*16 + lr) * 64 + ks*32 + lk);
#pragma unroll
            for (int nj = 0; nj < 4; ++nj)
                b[nj] = *reinterpret_cast<const short8*>(Bl + (wc + nj*16 + lr) * 64 + ks*32 + lk);
#pragma unroll
            for (int mi = 0; mi < 4; ++mi)
#pragma unroll
                for (int nj = 0; nj < 4; ++nj)
                    acc[mi][nj] = __builtin_amdgcn_mfma_f32_16x16x32_bf16(a[mi], b[nj], acc[mi][nj], 0, 0, 0);
        }
    }
#pragma unroll
    for (int mi = 0; mi < 4; ++mi) {
#pragma unroll
        for (int nj = 0; nj < 4; ++nj) {
            int r = m0 + wr + mi*16 + lg*4;
            int c = n0 + wc + nj*16 + lr;
            if (VSPLIT && c >= 2048) {
                int cc = c - 2048;
                int bh = ((r >> 11) << 4) + (cc >> 6);
                int d = cc & 63;
                ushort4 o4;
                o4.x = f2bf(acc[mi][nj][0]);
                o4.y = f2bf(acc[mi][nj][1]);
                o4.z = f2bf(acc[mi][nj][2]);
                o4.w = f2bf(acc[mi][nj][3]);
                *reinterpret_cast<ushort4*>(vTp + ((size_t)(bh * 64 + d) * 2048) + (r & 2047)) = o4;
            } else {
                float bv = BIAS ? bias[c] : 0.f;
#pragma unroll
                for (int i = 0; i < 4; ++i) {
                    float v = acc[mi][nj][i] + bv;
                    if (OUT_BF16)
                        reinterpret_cast<unsigned short*>(Cv)[(size_t)(r + i) * N + c] = f2bf(v);
                    else
                        reinterpret_cast<float*>(Cv)[(size_t)(r + i) * N + c] = v;
                }
            }
        }
    }
}

// ---------------- flash attention (R7 config, best measured): 64 q/wave, dbuf K/V, ----------------
// fragment-linear LDS (contiguous 1KB fragment blocks), P via per-wave LDS tile,
// defer-max (T13), setprio (T5), reg-staged K/V with next-tile loads issued under compute.
__global__ __launch_bounds__(256, 2) void attn_kernel(const unsigned short* __restrict__ qkv,
                                                      const unsigned short* __restrict__ vT,
                                                      unsigned short* __restrict__ attn_o) {
    __shared__ unsigned short Kl[2 * 64 * 64];   // double-buffered, 8192 B each
    __shared__ unsigned short Vl[2 * 64 * 64];
    __shared__ unsigned short Pl[4 * 64 * 64];   // per-wave 8192 B (subtile A, then B)

    // bijective XCD-chunked swizzle: 512 blocks = 8 XCDs x 64
    int w = blockIdx.x;
    int lid = (w & 7) * 64 + (w >> 3);
    int bh = lid >> 3, qb = lid & 7;
    int b = bh >> 4, h = bh & 15;

    int tid = threadIdx.x, lane = tid & 63, wv = tid >> 6;
    int lr = lane & 31, hi = lane >> 5;
    int q0 = qb * 256 + wv * 64;

    // Q b-frags for both subtiles: qf[ks] elem j = Q[q][ks*16 + hi*8 + j]  (assumed map)
    short8 qfA[4], qfB[4];
    {
        const unsigned short* qrowA = qkv + (size_t)(b * Nseq + q0 + lr) * 3072 + h * 64 + hi * 8;
        const unsigned short* qrowB = qrowA + (size_t)32 * 3072;
#pragma unroll
        for (int ks = 0; ks < 4; ++ks) {
            qfA[ks] = *reinterpret_cast<const short8*>(qrowA + ks * 16);
            qfB[ks] = *reinterpret_cast<const short8*>(qrowB + ks * 16);
        }
    }

    float mrunA = -1e30f, lrunA = 0.f, mrunB = -1e30f, lrunB = 0.f;
    f32x16 oA0 = (f32x16)0.f, oA1 = (f32x16)0.f, oB0 = (f32x16)0.f, oB1 = (f32x16)0.f;

    // staging: thread t covers K row sr (kv), d block (tid&3)*16  /  V row sr (d), kv block (tid&3)*16
    int sr = tid >> 2;
    const unsigned short* kg = qkv + (size_t)(b * Nseq + sr) * 3072 + 1024 + h * 64 + (tid & 3) * 16;
    const unsigned short* vg = vT + ((size_t)(bh * 64 + sr)) * Nseq + (tid & 3) * 16;
    // fragment-linear staging offset (chunk0; chunk1 = +512): same formula for K and V tiles
    int sb = (sr >> 5) * 4096 + (tid & 3) * 1024 + (sr & 31) * 16;
    char* Pw = (char*)Pl + wv * 8192 + lr * 16 + 8 * hi;   // + (t>>1)*1024 + (t&1)*512 per b64
    char* Pr = (char*)Pl + wv * 8192 + lane * 16;          // + ks4*1024 (subtile A), +4096 (B)

    // prologue: stage tile 0 into buffer 0
    {
        ushort8 a0 = *reinterpret_cast<const ushort8*>(kg);
        ushort8 a1 = *reinterpret_cast<const ushort8*>(kg + 8);
        ushort8 a2 = *reinterpret_cast<const ushort8*>(vg);
        ushort8 a3 = *reinterpret_cast<const ushort8*>(vg + 8);
        *reinterpret_cast<ushort8*>((char*)Kl + sb) = a0;
        *reinterpret_cast<ushort8*>((char*)Kl + sb + 512) = a1;
        *reinterpret_cast<ushort8*>((char*)Vl + sb) = a2;
        *reinterpret_cast<ushort8*>((char*)Vl + sb + 512) = a3;
    }
    // issue tile 1 loads
    ushort8 k0r = *reinterpret_cast<const ushort8*>(kg + (size_t)64 * 3072);
    ushort8 k1r = *reinterpret_cast<const ushort8*>(kg + (size_t)64 * 3072 + 8);
    ushort8 v0r = *reinterpret_cast<const ushort8*>(vg + 64);
    ushort8 v1r = *reinterpret_cast<const ushort8*>(vg + 72);

    int cur = 0;
    for (int jt = 0; jt < Nseq; jt += 64, cur ^= 1) {
        __syncthreads();   // buf[cur] fully written by all waves
        int rb = cur * 8192, wb = rb ^ 8192;

        // ---- S^T = K · Q^T : kf reads are contiguous 1KB blocks, conflict-free ----
        f32x16 sA0 = (f32x16)0.f, sA1 = (f32x16)0.f, sB0 = (f32x16)0.f, sB1 = (f32x16)0.f;
        __builtin_amdgcn_s_setprio(1);
#pragma unroll
        for (int ks = 0; ks < 4; ++ks) {
            short8 kf0 = *reinterpret_cast<const short8*>((char*)Kl + rb + ks*1024 + lane*16);
            short8 kf1 = *reinterpret_cast<const short8*>((char*)Kl + rb + 4096 + ks*1024 + lane*16);
            sA0 = __builtin_amdgcn_mfma_f32_32x32x16_bf16(kf0, qfA[ks], sA0, 0, 0, 0);
            sA1 = __builtin_amdgcn_mfma_f32_32x32x16_bf16(kf1, qfA[ks], sA1, 0, 0, 0);
            sB0 = __builtin_amdgcn_mfma_f32_32x32x16_bf16(kf0, qfB[ks], sB0, 0, 0, 0);
            sB1 = __builtin_amdgcn_mfma_f32_32x32x16_bf16(kf1, qfB[ks], sB1, 0, 0, 0);
        }
        __builtin_amdgcn_s_setprio(0);

        // ---- stage tile t+1 into buf[cur^1] (off critical path) ----
        if (jt + 64 < Nseq) {
            *reinterpret_cast<ushort8*>((char*)Kl + wb + sb) = k0r;
            *reinterpret_cast<ushort8*>((char*)Kl + wb + sb + 512) = k1r;
            *reinterpret_cast<ushort8*>((char*)Vl + wb + sb) = v0r;
            *reinterpret_cast<ushort8*>((char*)Vl + wb + sb + 512) = v1r;
            int jn = jt + 128;
            if (jn < Nseq) {
                k0r = *reinterpret_cast<const ushort8*>(kg + (size_t)jn * 3072);
                k1r = *reinterpret_cast<const ushort8*>(kg + (size_t)jn * 3072 + 8);
                v0r = *reinterpret_cast<const ushort8*>(vg + jn);
                v1r = *reinterpret_cast<const ushort8*>(vg + jn + 8);
            }
        }

        // ---- per-lane tile max for both subtiles ----
        float tA[16], tB[16];
#pragma unroll
        for (int i = 0; i < 16; ++i) { tA[i] = fmaxf(sA0[i], sA1[i]); tB[i] = fmaxf(sB0[i], sB1[i]); }
#pragma unroll
        for (int st = 8; st > 0; st >>= 1)
#pragma unroll
            for (int i = 0; i < st; ++i) { tA[i] = fmaxf(tA[i], tA[i + st]); tB[i] = fmaxf(tB[i], tB[i + st]); }
        float mlocA = fmaxf(tA[0], __shfl_xor(tA[0], 32)) * SCALE;
        float mlocB = fmaxf(tB[0], __shfl_xor(tB[0], 32)) * SCALE;

        // ---- defer-max (T13): rescale only when max grew > 8 ----
        if (!__all((mlocA <= mrunA + 8.f) && (mlocB <= mrunB + 8.f))) {
            float mnA = fmaxf(mrunA, mlocA);
            float fA = __builtin_amdgcn_exp2f((mrunA - mnA) * L2E);
            float mnB = fmaxf(mrunB, mlocB);
            float fB = __builtin_amdgcn_exp2f((mrunB - mnB) * L2E);
            lrunA *= fA; lrunB *= fB; mrunA = mnA; mrunB = mnB;
#pragma unroll
            for (int i = 0; i < 16; ++i) {
                oA0[i] *= fA; oA1[i] *= fA; oB0[i] *= fB; oB1[i] *= fB;
            }
        }

        // ---- P = exp2(s*c1 + c0) ----
        const float c1 = SCALE * L2E;
        float c0A = -mrunA * L2E, c0B = -mrunB * L2E;
        float pA0[16], pA1[16], pB0[16], pB1[16];
#pragma unroll
        for (int i = 0; i < 16; ++i) {
            pA0[i] = __builtin_amdgcn_exp2f(fmaf(sA0[i], c1, c0A));
            pA1[i] = __builtin_amdgcn_exp2f(fmaf(sA1[i], c1, c0A));
            pB0[i] = __builtin_amdgcn_exp2f(fmaf(sB0[i], c1, c0B));
            pB1[i] = __builtin_amdgcn_exp2f(fmaf(sB1[i], c1, c0B));
        }

        // ---- pack + write P, fragment-linear b64 stores (conflict-free) ----
        uint32_t WA[16], WB[16];
#pragma unroll
        for (int m = 0; m < 8; ++m) {
            asm("v_cvt_pk_bf16_f32 %0, %1, %2" : "=v"(WA[m])   : "v"(pA0[2*m]), "v"(pA0[2*m+1]));
            asm("v_cvt_pk_bf16_f32 %0, %1, %2" : "=v"(WA[8+m]) : "v"(pA1[2*m]), "v"(pA1[2*m+1]));
            asm("v_cvt_pk_bf16_f32 %0, %1, %2" : "=v"(WB[m])   : "v"(pB0[2*m]), "v"(pB0[2*m+1]));
            asm("v_cvt_pk_bf16_f32 %0, %1, %2" : "=v"(WB[8+m]) : "v"(pB1[2*m]), "v"(pB1[2*m+1]));
        }
#pragma unroll
        for (int tt = 0; tt < 8; ++tt) {
            uint64_t valA = (uint64_t)WA[2*tt] | ((uint64_t)WA[2*tt+1] << 32);
            uint64_t valB = (uint64_t)WB[2*tt] | ((uint64_t)WB[2*tt+1] << 32);
            char* pa = Pw + (tt >> 1) * 1024 + (tt & 1) * 512;
            *reinterpret_cast<uint64_t*>(pa) = valA;
            *reinterpret_cast<uint64_t*>(pa + 4096) = valB;
        }

        float aA[16], aB[16];
#pragma unroll
        for (int i = 0; i < 16; ++i) { aA[i] = pA0[i] + pA1[i]; aB[i] = pB0[i] + pB1[i]; }
#pragma unroll
        for (int st = 8; st > 0; st >>= 1)
#pragma unroll
            for (int i = 0; i < st; ++i) { aA[i] += aA[i + st]; aB[i] += aB[i + st]; }
        lrunA += aA[0] + __shfl_xor(aA[0], 32);
        lrunB += aB[0] + __shfl_xor(aB[0], 32);

        // ---- O^T += V^T · P : all reads contiguous 1KB fragment blocks ----
        __builtin_amdgcn_s_setprio(1);
#pragma unroll
        for (int ks4 = 0; ks4 < 4; ++ks4) {
            short8 vf0 = *reinterpret_cast<const short8*>((char*)Vl + rb + ks4*1024 + lane*16);
            short8 vf1 = *reinterpret_cast<const short8*>((char*)Vl + rb + 4096 + ks4*1024 + lane*16);
            short8 pfA = *reinterpret_cast<const short8*>(Pr + ks4*1024);
            short8 pfB = *reinterpret_cast<const short8*>(Pr + 4096 + ks4*1024);
            oA0 = __builtin_amdgcn_mfma_f32_32x32x16_bf16(vf0, pfA, oA0, 0, 0, 0);
            oA1 = __builtin_amdgcn_mfma_f32_32x32x16_bf16(vf1, pfA, oA1, 0, 0, 0);
            oB0 = __builtin_amdgcn_mfma_f32_32x32x16_bf16(vf0, pfB, oB0, 0, 0, 0);
            oB1 = __builtin_amdgcn_mfma_f32_32x32x16_bf16(vf1, pfB, oB1, 0, 0, 0);
        }
        __builtin_amdgcn_s_setprio(0);
    }

    // ---- epilogue: O^T[d][q] -> attn_o[b*N + q][h*64 + d] ----
    float invA = 1.f / lrunA, invB = 1.f / lrunB;
    unsigned short* orowA = attn_o + (size_t)(b * Nseq + q0 + lr) * Dmod + h * 64;
    unsigned short* orowB = attn_o + (size_t)(b * Nseq + q0 + 32 + lr) * Dmod + h * 64;
#pragma unroll
    for (int db = 0; db < 2; ++db)
#pragma unroll
        for (int g = 0; g < 4; ++g) {
            int d = db * 32 + 8 * g + 4 * hi;
            ushort4 o4;
            o4.x = f2bf((db ? oA1[4*g+0] : oA0[4*g+0]) * invA);
            o4.y = f2bf((db ? oA1[4*g+1] : oA0[4*g+1]) * invA);
            o4.z = f2bf((db ? oA1[4*g+2] : oA0[4*g+2]) * invA);
            o4.w = f2bf((db ? oA1[4*g+3] : oA0[4*g+3]) * invA);
            *reinterpret_cast<ushort4*>(orowA + d) = o4;
            o4.x = f2bf((db ? oB1[4*g+0] : oB0[4*g+0]) * invB);
            o4.y = f2bf((db ? oB1[4*g+1] : oB0[4*g+1]) * invB);
            o4.z = f2bf((db ? oB1[4*g+2] : oB0[4*g+2]) * invB);
            o4.w = f2bf((db ? oB1[4*g+3] : oB0[4*g+3]) * invB);
            *reinterpret_cast<ushort4*>(orowB + d) = o4;
        }
}

// ---------------- launch ----------------
extern "C" void kernel_launch(void* const* d_in, const int* in_sizes, int n_in,
                              void* d_out, int out_size, void* d_ws, size_t ws_size,
                              hipStream_t stream) {
    const float* x      = (const float*)d_in[0];
    const float* w_qkv  = (const float*)d_in[1];
    const float* w_proj = (const float*)d_in[2];
    const float* b_proj = (const float*)d_in[3];
    float* out = (float*)d_out;
    char* ws = (char*)d_ws;

    unsigned short* qkv    = (unsigned short*)(ws);               // 50331648 B (V third unused)
    unsigned short* vT     = (unsigned short*)(ws + 50331648);    // 16777216 B
    unsigned short* xb     = (unsigned short*)(ws + 67108864);    // 16777216 B (reused as attn_o)
    unsigned short* attn_o = xb;
    unsigned short* wqkvT  = (unsigned short*)(ws + 83886080);    // 6291456 B
    unsigned short* wprojT = (unsigned short*)(ws + 90177536);    // 2097152 B

    prep_kernel<<<6144, 256, 0, stream>>>(x, w_qkv, w_proj, xb, wqkvT, wprojT);
    // qkv = x @ w_qkv; V columns redirected (transposed) into vT
    gemm_bt_kernel<true, false, true><<<dim3(3072/128, 8192/128), 256, 0, stream>>>(
        xb, wqkvT, qkv, nullptr, vT, Bdim*Nseq, 3*Dmod, Dmod);
    attn_kernel<<<512, 256, 0, stream>>>(qkv, vT, attn_o);
    gemm_bt_kernel<false, true, false><<<dim3(1024/128, 8192/128), 256, 0, stream>>>(
        attn_o, wprojT, out, b_proj, nullptr, Bdim*Nseq, Dmod, Dmod);
}